// Round 5
// baseline (1344.094 us; speedup 1.0000x reference)
//
#include <hip/hip_runtime.h>
#include <stdint.h>

typedef unsigned char u8;
typedef unsigned short us;
typedef unsigned int u32;

#define CDIM  128
#define KNBR  48
#define HEADS 8
#define DHEAD 16
#define FFDIM 256

using bf16x8 = __attribute__((ext_vector_type(8))) short;  // 8 bf16 (4 VGPRs)
using f32x4  = __attribute__((ext_vector_type(4))) float;  // 4 fp32

__device__ inline float blo32(u32 u) { union { u32 i; float f; } v; v.i = u << 16; return v.f; }
__device__ inline float bhi32(u32 u) { union { u32 i; float f; } v; v.i = u & 0xFFFF0000u; return v.f; }
__device__ inline float bf2f(us u) { union { u32 i; float f; } v; v.i = ((u32)u) << 16; return v.f; }
__device__ inline us f2bf(float x) {
    union { float f; u32 i; } v; v.f = x;
    u32 r = v.i + 0x7FFFu + ((v.i >> 16) & 1u);
    return (us)(r >> 16);
}

// ---------------------------------------------------------------------------
// K0: probe key_mask storage (int32 vs u8 bool). flag=1 -> u8 storage.
// ---------------------------------------------------------------------------
__global__ void k_mask_probe(const u32* __restrict__ mw, int nwords,
                             int* __restrict__ flag)
{
    u32 any = 0;
    for (int j = blockIdx.x * blockDim.x + threadIdx.x; j < nwords;
         j += gridDim.x * blockDim.x)
        any |= mw[j] & 0xFFFFFF00u;
    if (any) atomicOr(flag, 1);
}

// ---------------------------------------------------------------------------
// K1: QKV projection.  QKV = F @ in_proj_w^T + in_proj_b, split into Q/Fk/Fv.
// ---------------------------------------------------------------------------
__global__ __launch_bounds__(384) void k_qkv(
    const float* __restrict__ F, const float* __restrict__ W,
    const float* __restrict__ B,
    float* __restrict__ Q, float* __restrict__ Fk, float* __restrict__ Fv, int N)
{
    __shared__ float xL[8][CDIM];
    int row0 = blockIdx.x * 8;
    int t = threadIdx.x;
    for (int o = t; o < 8 * CDIM; o += 384) {
        int r = o >> 7, c = o & 127;
        int row = row0 + r;
        xL[r][c] = (row < N) ? F[row * CDIM + c] : 0.f;
    }
    __syncthreads();

    int e = t;  // 0..383
    const float4* W4 = (const float4*)(W + e * CDIM);
    float acc[8] = {0.f,0.f,0.f,0.f,0.f,0.f,0.f,0.f};
    #pragma unroll 8
    for (int c4 = 0; c4 < CDIM / 4; ++c4) {
        float4 w = W4[c4];
        #pragma unroll
        for (int r = 0; r < 8; ++r) {
            const float* x = &xL[r][c4 * 4];
            acc[r] += x[0]*w.x + x[1]*w.y + x[2]*w.z + x[3]*w.w;
        }
    }
    float bv = B[e];
    float* dst; int eo;
    if (e < 128)      { dst = Q;  eo = e; }
    else if (e < 256) { dst = Fk; eo = e - 128; }
    else              { dst = Fv; eo = e - 256; }
    #pragma unroll
    for (int r = 0; r < 8; ++r) {
        int row = row0 + r;
        if (row < N) dst[row * CDIM + eo] = acc[r] + bv;
    }
}

// ---------------------------------------------------------------------------
// K2: attention, one block (256 thr = 4 waves) per query voxel.
// LDS-throughput-bound in R4 -> move qw.P scores to MFMA (hi/lo bf16 split,
// f32-grade precision: rel err ~2^-17) and shrink Pbar to one wave reading
// the hi plane only (0.4% rel on the pos-V path, ~0.01 final).
//   score[h,k] = ( q_h . Fk[idx_k]_h  [f32, wave 3]
//               + qw[h,:] . P[k,:]    [MFMA, waves 0-2] ) / 4
//   ctx[c]     = sum_k a[h,k] Fv[idx_k][c]  +  Pbar[h,:] . wv[c,:]
// LDS 38752 B -> 4 blocks/CU.
// ---------------------------------------------------------------------------
__global__ __launch_bounds__(256, 4) void k_attn(
    const float* __restrict__ coords, const int* __restrict__ kidx,
    const u8* __restrict__ kmask_u8, const int* __restrict__ kmask_i32,
    const int* __restrict__ maskflag,
    const float* __restrict__ Q, const float* __restrict__ Fk,
    const float* __restrict__ Fv,
    const float* __restrict__ wk, const float* __restrict__ wv,
    const float* __restrict__ kpw, const float* __restrict__ kpb,
    float* __restrict__ CTX)
{
    // manual LDS layout (bytes):
    //   P_hi  us[48][136]  @ 0      .. 13056
    //   P_lo  us[48][136]  @ 13056  .. 26112
    //   qw_hi us[16][136]  @ 26112  .. 30464  (aliased by Pbar f32[8][132] in E/F)
    //   qw_lo us[16][136]  @ 30464  .. 34816
    //   scL   f32[8][49]   @ 34816  .. 36384  (49 stride: conflict-free bcast)
    //   Ql    f32[128]     @ 36384  .. 36896
    //   rel   f32[48*3]    @ 36896  .. 37472
    //   idxl  i32[48]      @ 37472  .. 37664
    //   mskl  u8[48]       @ 37664  .. 37728
    //   pc    f32[2][128]  @ 37728  .. 38752
    __shared__ __align__(16) u8 SM[38752];
    us*    PH   = (us*)(SM);
    us*    PL   = (us*)(SM + 13056);
    us*    qwH  = (us*)(SM + 26112);
    us*    qwL  = (us*)(SM + 30464);
    float* Pb   = (float*)(SM + 26112);   // Pbar alias (qw dead after MFMA)
    float* scL  = (float*)(SM + 34816);
    float* Ql   = (float*)(SM + 36384);
    float* rel  = (float*)(SM + 36896);
    int*   idxl = (int*)  (SM + 37472);
    u8*    mskl = (u8*)   (SM + 37664);
    float* pc   = (float*)(SM + 37728);

    int n = blockIdx.x;
    int t = threadIdx.x;
    int w = t >> 6, lane = t & 63;

    // ---- phase A: indices / mask / rel coords / q row ----
    if (t < KNBR) {
        int idx = kidx[n * KNBR + t];
        idxl[t] = idx;
        mskl[t] = maskflag[0] ? kmask_u8[n * KNBR + t]
                              : (u8)kmask_i32[n * KNBR + t];
        rel[t * 3 + 0] = coords[idx * 3 + 0] - coords[n * 3 + 0];
        rel[t * 3 + 1] = coords[idx * 3 + 1] - coords[n * 3 + 1];
        rel[t * 3 + 2] = coords[idx * 3 + 2] - coords[n * 3 + 2];
    } else if (t >= 128) {
        Ql[t - 128] = Q[n * CDIM + (t - 128)];
    }
    __syncthreads();

    // ---- phase B: qw = q_h @ wk_h (f32 -> hi/lo bf16) ; P likewise ----
    {
        int h = t >> 5, c4 = t & 31;
        const float* qh = Ql + h * DHEAD;
        float a0=0.f, a1=0.f, a2=0.f, a3=0.f;
        #pragma unroll
        for (int d = 0; d < DHEAD; ++d) {
            float q = qh[d];
            float4 wr = *(const float4*)(wk + (size_t)(h * DHEAD + d) * CDIM + c4 * 4);
            a0 += q * wr.x; a1 += q * wr.y; a2 += q * wr.z; a3 += q * wr.w;
        }
        us h0=f2bf(a0), h1=f2bf(a1), h2=f2bf(a2), h3=f2bf(a3);
        us l0=f2bf(a0-bf2f(h0)), l1=f2bf(a1-bf2f(h1)),
           l2=f2bf(a2-bf2f(h2)), l3=f2bf(a3-bf2f(h3));
        uint2 ph; ph.x = (u32)h0 | ((u32)h1 << 16); ph.y = (u32)h2 | ((u32)h3 << 16);
        uint2 pl; pl.x = (u32)l0 | ((u32)l1 << 16); pl.y = (u32)l2 | ((u32)l3 << 16);
        *(uint2*)&qwH[h * 136 + c4 * 4] = ph;
        *(uint2*)&qwL[h * 136 + c4 * 4] = pl;
    }
    // zero qw rows 8..15 (both planes): rows 8..15 = us 1088.. = u32 544..1087
    for (int o = t; o < 1088; o += 256) {
        int plane = (o >= 544); int wd = o - plane * 544;
        ((u32*)(plane ? (void*)qwL : (void*)qwH))[544 + wd] = 0u;
    }
    #pragma unroll
    for (int it = 0; it < 6; ++it) {
        int o = t + it * 256;                 // 1536 = 48 k x 32 c-quads
        int k = o >> 5, c4 = o & 31;
        float r0 = rel[k * 3], r1 = rel[k * 3 + 1], r2 = rel[k * 3 + 2];
        const float4* kw = (const float4*)(kpw + c4 * 12);
        float4 wa = kw[0], wb = kw[1], wc = kw[2];
        float4 bb = ((const float4*)kpb)[c4];
        float p0 = fmaxf(bb.x + r0 * wa.x + r1 * wa.y + r2 * wa.z, 0.f);
        float p1 = fmaxf(bb.y + r0 * wa.w + r1 * wb.x + r2 * wb.y, 0.f);
        float p2 = fmaxf(bb.z + r0 * wb.z + r1 * wb.w + r2 * wc.x, 0.f);
        float p3 = fmaxf(bb.w + r0 * wc.y + r1 * wc.z + r2 * wc.w, 0.f);
        us h0=f2bf(p0), h1=f2bf(p1), h2=f2bf(p2), h3=f2bf(p3);
        us l0=f2bf(p0-bf2f(h0)), l1=f2bf(p1-bf2f(h1)),
           l2=f2bf(p2-bf2f(h2)), l3=f2bf(p3-bf2f(h3));
        uint2 ph; ph.x = (u32)h0 | ((u32)h1 << 16); ph.y = (u32)h2 | ((u32)h3 << 16);
        uint2 pl; pl.x = (u32)l0 | ((u32)l1 << 16); pl.y = (u32)l2 | ((u32)l3 << 16);
        *(uint2*)&PH[k * 136 + c4 * 4] = ph;
        *(uint2*)&PL[k * 136 + c4 * 4] = pl;
    }
    __syncthreads();

    // ---- phase C: scores. wave 3: exact f32 q.Fk; waves 0-2: MFMA qw.P ----
    f32x4 acc = {0.f, 0.f, 0.f, 0.f};
    if (w == 3) {
        #pragma unroll
        for (int i = 0; i < 6; ++i) {
            int o = lane * 6 + i;             // 384 items
            int k = o >> 3, h = o & 7;
            const float* qh = Ql + h * DHEAD;
            const float4* fk = (const float4*)(Fk + (size_t)idxl[k] * CDIM + h * DHEAD);
            float4 f0 = fk[0], f1 = fk[1], f2 = fk[2], f3 = fk[3];
            float s = qh[0]*f0.x + qh[1]*f0.y + qh[2]*f0.z + qh[3]*f0.w
                    + qh[4]*f1.x + qh[5]*f1.y + qh[6]*f1.z + qh[7]*f1.w
                    + qh[8]*f2.x + qh[9]*f2.y + qh[10]*f2.z + qh[11]*f2.w
                    + qh[12]*f3.x + qh[13]*f3.y + qh[14]*f3.z + qh[15]*f3.w;
            scL[h * 49 + k] = s;
        }
    } else {
        int kt = w;                            // k-tile 0..2
        int row = lane & 15;
        int ko = (lane >> 4) * 8;
        const us* arH = qwH + row * 136;
        const us* arL = qwL + row * 136;
        const us* brH = PH + (kt * 16 + row) * 136;
        const us* brL = PL + (kt * 16 + row) * 136;
        #pragma unroll
        for (int s = 0; s < 4; ++s) {          // K = 128 over 4 steps of 32
            int c0 = s * 32 + ko;
            bf16x8 ah = *(const bf16x8*)(arH + c0);
            bf16x8 al = *(const bf16x8*)(arL + c0);
            bf16x8 bh = *(const bf16x8*)(brH + c0);
            bf16x8 bl = *(const bf16x8*)(brL + c0);
            acc = __builtin_amdgcn_mfma_f32_16x16x32_bf16(ah, bh, acc, 0, 0, 0);
            acc = __builtin_amdgcn_mfma_f32_16x16x32_bf16(ah, bl, acc, 0, 0, 0);
            acc = __builtin_amdgcn_mfma_f32_16x16x32_bf16(al, bh, acc, 0, 0, 0);
        }
    }
    __syncthreads();

    // combine MFMA acc + qk part, mask, scale (D: col=lane&15, row=(lane>>4)*4+j)
    if (w < 3 && lane < 32) {
        int kk = w * 16 + (lane & 15);
        int rb = (lane >> 4) * 4;
        u8 mk = mskl[kk];
        #pragma unroll
        for (int j = 0; j < 4; ++j) {
            int h = rb + j;
            float s = acc[j] + scL[h * 49 + kk];
            scL[h * 49 + kk] = mk ? -1e30f : s * 0.25f;
        }
    }
    __syncthreads();

    // ---- phase D: softmax (32 lanes per head) ----
    {
        int h = t >> 5, l32 = t & 31;
        float* sc = scL + h * 49;
        float v0 = sc[l32];
        float v1 = (l32 < KNBR - 32) ? sc[l32 + 32] : -1e30f;
        float m = fmaxf(v0, v1);
        #pragma unroll
        for (int off = 16; off >= 1; off >>= 1)
            m = fmaxf(m, __shfl_xor(m, off, 32));
        float e0 = __expf(v0 - m);
        float e1 = (l32 < KNBR - 32) ? __expf(v1 - m) : 0.f;
        float s = e0 + e1;
        #pragma unroll
        for (int off = 16; off >= 1; off >>= 1)
            s += __shfl_xor(s, off, 32);
        float inv = 1.f / s;
        sc[l32] = e0 * inv;
        if (l32 < KNBR - 32) sc[l32 + 32] = e1 * inv;
    }
    __syncthreads();

    // ---- phase E: Pbar[h][:] = attn[h,:] @ P_hi  (wave 3 only; hi plane) ----
    if (w == 3) {
        int h = lane >> 3;
        int cb = (lane & 7) * 16;              // 16 c's per lane
        float a[16];
        #pragma unroll
        for (int i = 0; i < 16; ++i) a[i] = 0.f;
        #pragma unroll 4
        for (int k = 0; k < KNBR; ++k) {
            float p = scL[h * 49 + k];
            uint4 r0 = *(const uint4*)&PH[k * 136 + cb];
            uint4 r1 = *(const uint4*)&PH[k * 136 + cb + 8];
            a[0]  += p * blo32(r0.x); a[1]  += p * bhi32(r0.x);
            a[2]  += p * blo32(r0.y); a[3]  += p * bhi32(r0.y);
            a[4]  += p * blo32(r0.z); a[5]  += p * bhi32(r0.z);
            a[6]  += p * blo32(r0.w); a[7]  += p * bhi32(r0.w);
            a[8]  += p * blo32(r1.x); a[9]  += p * bhi32(r1.x);
            a[10] += p * blo32(r1.y); a[11] += p * bhi32(r1.y);
            a[12] += p * blo32(r1.z); a[13] += p * bhi32(r1.z);
            a[14] += p * blo32(r1.w); a[15] += p * bhi32(r1.w);
        }
        #pragma unroll
        for (int j = 0; j < 4; ++j)
            *(float4*)&Pb[h * 132 + cb + j * 4] =
                make_float4(a[j*4], a[j*4+1], a[j*4+2], a[j*4+3]);
    }
    __syncthreads();

    // ---- phase F: ctx = attn @ Fv (coalesced gather) + Pbar . wv ----
    {
        int c = t & 127, half = t >> 7;
        int h = c >> 4;
        const float* sc = scL + h * 49;
        float accF = 0.f;
        #pragma unroll 4
        for (int kk = 0; kk < 24; ++kk) {
            int k = half * 24 + kk;
            accF += sc[k] * Fv[(size_t)idxl[k] * CDIM + c];
        }
        const float4* wr = (const float4*)(wv + (size_t)c * CDIM) + half * 16;
        const float4* pb4 = (const float4*)(Pb + h * 132) + half * 16;
        #pragma unroll 4
        for (int j = 0; j < 16; ++j) {
            float4 wq = wr[j], p = pb4[j];
            accF += wq.x*p.x + wq.y*p.y + wq.z*p.z + wq.w*p.w;
        }
        pc[half * 128 + c] = accF;
    }
    __syncthreads();
    if (t < CDIM) CTX[n * CDIM + t] = pc[t] + pc[128 + t];
}

// ---------------------------------------------------------------------------
// K3/K6: 128->128 GEMM + bias (+ optional residual) + LayerNorm (+ opt relu)
// ---------------------------------------------------------------------------
__global__ __launch_bounds__(256) void k_proj_ln(
    const float* __restrict__ X, const float* __restrict__ RES,
    const float* __restrict__ W, const float* __restrict__ B,
    const float* __restrict__ G, const float* __restrict__ LB,
    float* __restrict__ OUT, int N, int relu_out)
{
    __shared__ float xL[16][CDIM];
    __shared__ float aL[16][CDIM + 4];
    __shared__ float mu[16], rs[16];
    int row0 = blockIdx.x * 16;
    int t = threadIdx.x;
    for (int o = t; o < 16 * CDIM; o += 256) {
        int r = o >> 7, c = o & 127;
        int row = row0 + r;
        xL[r][c] = (row < N) ? X[row * CDIM + c] : 0.f;
    }
    __syncthreads();

    int e = t & 127, rh = t >> 7;
    const float4* W4 = (const float4*)(W + e * CDIM);
    float acc[8] = {0.f,0.f,0.f,0.f,0.f,0.f,0.f,0.f};
    #pragma unroll 8
    for (int c4 = 0; c4 < CDIM / 4; ++c4) {
        float4 w = W4[c4];
        #pragma unroll
        for (int i = 0; i < 8; ++i) {
            const float* x = &xL[rh * 8 + i][c4 * 4];
            acc[i] += x[0]*w.x + x[1]*w.y + x[2]*w.z + x[3]*w.w;
        }
    }
    float bv = B[e];
    #pragma unroll
    for (int i = 0; i < 8; ++i) {
        int r = rh * 8 + i, row = row0 + r;
        float a = acc[i] + bv;
        if (RES != nullptr && row < N) a += RES[row * CDIM + e];
        aL[r][e] = a;
    }
    __syncthreads();

    {
        int r = t >> 4, j = t & 15;
        float s = 0.f;
        #pragma unroll
        for (int jj = 0; jj < 8; ++jj) s += aL[r][j * 8 + jj];
        #pragma unroll
        for (int off = 8; off >= 1; off >>= 1) s += __shfl_xor(s, off, 16);
        float mean = s * (1.f / 128.f);
        float v = 0.f;
        #pragma unroll
        for (int jj = 0; jj < 8; ++jj) {
            float d = aL[r][j * 8 + jj] - mean; v += d * d;
        }
        #pragma unroll
        for (int off = 8; off >= 1; off >>= 1) v += __shfl_xor(v, off, 16);
        if (j == 0) { mu[r] = mean; rs[r] = rsqrtf(v * (1.f / 128.f) + 1e-5f); }
    }
    __syncthreads();

    for (int o = t; o < 16 * CDIM; o += 256) {
        int r = o >> 7, c = o & 127;
        int row = row0 + r;
        if (row < N) {
            float y = (aL[r][c] - mu[r]) * rs[r] * G[c] + LB[c];
            if (relu_out) y = fmaxf(y, 0.f);
            OUT[row * CDIM + c] = y;
        }
    }
}

// ---------------------------------------------------------------------------
// K4: ff1: hid = relu(x1 @ W1^T + b1), 128 -> 256.
// ---------------------------------------------------------------------------
__global__ __launch_bounds__(256) void k_ff1(
    const float* __restrict__ X, const float* __restrict__ W,
    const float* __restrict__ B, float* __restrict__ HID, int N)
{
    __shared__ float xL[8][CDIM];
    int row0 = blockIdx.x * 8;
    int t = threadIdx.x;
    for (int o = t; o < 8 * CDIM; o += 256) {
        int r = o >> 7, c = o & 127;
        int row = row0 + r;
        xL[r][c] = (row < N) ? X[row * CDIM + c] : 0.f;
    }
    __syncthreads();

    int e = t;
    const float4* W4 = (const float4*)(W + e * CDIM);
    float acc[8] = {0.f,0.f,0.f,0.f,0.f,0.f,0.f,0.f};
    #pragma unroll 8
    for (int c4 = 0; c4 < CDIM / 4; ++c4) {
        float4 w = W4[c4];
        #pragma unroll
        for (int r = 0; r < 8; ++r) {
            const float* x = &xL[r][c4 * 4];
            acc[r] += x[0]*w.x + x[1]*w.y + x[2]*w.z + x[3]*w.w;
        }
    }
    float bv = B[e];
    #pragma unroll
    for (int r = 0; r < 8; ++r) {
        int row = row0 + r;
        if (row < N) HID[row * FFDIM + e] = fmaxf(acc[r] + bv, 0.f);
    }
}

// ---------------------------------------------------------------------------
// K5: x2 = LN(x1 + hid @ W2^T + b2), 256 -> 128.
// ---------------------------------------------------------------------------
__global__ __launch_bounds__(256) void k_ff2_ln(
    const float* __restrict__ HID, const float* __restrict__ RES,
    const float* __restrict__ W, const float* __restrict__ B,
    const float* __restrict__ G, const float* __restrict__ LB,
    float* __restrict__ OUT, int N)
{
    __shared__ float xL[16][FFDIM];
    __shared__ float aL[16][CDIM + 4];
    __shared__ float mu[16], rs[16];
    int row0 = blockIdx.x * 16;
    int t = threadIdx.x;
    for (int o = t; o < 16 * FFDIM; o += 256) {
        int r = o >> 8, c = o & 255;
        int row = row0 + r;
        xL[r][c] = (row < N) ? HID[row * FFDIM + c] : 0.f;
    }
    __syncthreads();

    int e = t & 127, rh = t >> 7;
    const float4* W4 = (const float4*)(W + e * FFDIM);
    float acc[8] = {0.f,0.f,0.f,0.f,0.f,0.f,0.f,0.f};
    #pragma unroll 8
    for (int c4 = 0; c4 < FFDIM / 4; ++c4) {
        float4 w = W4[c4];
        #pragma unroll
        for (int i = 0; i < 8; ++i) {
            const float* x = &xL[rh * 8 + i][c4 * 4];
            acc[i] += x[0]*w.x + x[1]*w.y + x[2]*w.z + x[3]*w.w;
        }
    }
    float bv = B[e];
    #pragma unroll
    for (int i = 0; i < 8; ++i) {
        int r = rh * 8 + i, row = row0 + r;
        float a = acc[i] + bv;
        if (row < N) a += RES[row * CDIM + e];
        aL[r][e] = a;
    }
    __syncthreads();

    {
        int r = t >> 4, j = t & 15;
        float s = 0.f;
        #pragma unroll
        for (int jj = 0; jj < 8; ++jj) s += aL[r][j * 8 + jj];
        #pragma unroll
        for (int off = 8; off >= 1; off >>= 1) s += __shfl_xor(s, off, 16);
        float mean = s * (1.f / 128.f);
        float v = 0.f;
        #pragma unroll
        for (int jj = 0; jj < 8; ++jj) {
            float d = aL[r][j * 8 + jj] - mean; v += d * d;
        }
        #pragma unroll
        for (int off = 8; off >= 1; off >>= 1) v += __shfl_xor(v, off, 16);
        if (j == 0) { mu[r] = mean; rs[r] = rsqrtf(v * (1.f / 128.f) + 1e-5f); }
    }
    __syncthreads();

    for (int o = t; o < 16 * CDIM; o += 256) {
        int r = o >> 7, c = o & 127;
        int row = row0 + r;
        if (row < N)
            OUT[row * CDIM + c] = (aL[r][c] - mu[r]) * rs[r] * G[c] + LB[c];
    }
}

// ---------------------------------------------------------------------------
extern "C" void kernel_launch(void* const* d_in, const int* in_sizes, int n_in,
                              void* d_out, int out_size, void* d_ws, size_t ws_size,
                              hipStream_t stream)
{
    const float* F      = (const float*)d_in[0];
    const float* coords = (const float*)d_in[1];
    const int*   kidx   = (const int*)d_in[2];
    const void*  kmask  = d_in[3];
    const float* ipw    = (const float*)d_in[4];
    const float* ipb    = (const float*)d_in[5];
    const float* opw    = (const float*)d_in[6];
    const float* opb    = (const float*)d_in[7];
    const float* kpw    = (const float*)d_in[8];
    const float* kpb    = (const float*)d_in[9];
    const float* ln1g   = (const float*)d_in[10];
    const float* ln1b   = (const float*)d_in[11];
    const float* ln2g   = (const float*)d_in[12];
    const float* ln2b   = (const float*)d_in[13];
    const float* w1     = (const float*)d_in[14];
    const float* b1     = (const float*)d_in[15];
    const float* w2     = (const float*)d_in[16];
    const float* b2     = (const float*)d_in[17];
    const float* ow     = (const float*)d_in[18];
    const float* ob     = (const float*)d_in[19];
    const float* ln3g   = (const float*)d_in[20];
    const float* ln3b   = (const float*)d_in[21];

    int N = in_sizes[0] / CDIM;
    size_t NC = (size_t)N * CDIM;

    float* ws  = (float*)d_ws;
    float* Q   = ws;                 // N*128
    float* Fk  = ws + NC;            // N*128
    float* Fv  = ws + 2 * NC;        // N*128
    float* CTX = ws + 3 * NC;        // N*128
    float* X1  = Q;                  // reuse (Q dead after attention)
    float* HID = ws + NC;            // N*256, over Fk+Fv (dead after attention)
    float* X2  = CTX;                // reuse (CTX dead after K3)
    int* mflag = (int*)(ws + 4 * NC);

    const float* wk = ipw + CDIM * CDIM;
    const float* wv = ipw + 2 * CDIM * CDIM;

    hipMemsetAsync(mflag, 0, sizeof(int), stream);
    int nwords = (N * KNBR) / 4;
    k_mask_probe<<<256, 256, 0, stream>>>((const u32*)kmask, nwords, mflag);

    k_qkv<<<(N + 7) / 8, 384, 0, stream>>>(F, ipw, ipb, Q, Fk, Fv, N);
    k_attn<<<N, 256, 0, stream>>>(coords, kidx, (const u8*)kmask,
                                  (const int*)kmask, mflag, Q, Fk, Fv,
                                  wk, wv, kpw, kpb, CTX);
    k_proj_ln<<<(N + 15) / 16, 256, 0, stream>>>(CTX, F, opw, opb,
                                                 ln1g, ln1b, X1, N, 0);
    k_ff1<<<(N + 7) / 8, 256, 0, stream>>>(X1, w1, b1, HID, N);
    k_ff2_ln<<<(N + 15) / 16, 256, 0, stream>>>(HID, X1, w2, b2,
                                                ln2g, ln2b, X2, N);
    k_proj_ln<<<(N + 15) / 16, 256, 0, stream>>>(X2, nullptr, ow, ob,
                                                 ln3g, ln3b, (float*)d_out, N, 1);
}

// Round 6
// 1189.379 us; speedup vs baseline: 1.1301x; 1.1301x over previous
//
#include <hip/hip_runtime.h>
#include <stdint.h>

typedef unsigned char u8;
typedef unsigned short us;
typedef unsigned int u32;

#define CDIM  128
#define KNBR  48
#define HEADS 8
#define DHEAD 16
#define FFDIM 256

using bf16x8 = __attribute__((ext_vector_type(8))) short;  // 8 bf16 (4 VGPRs)
using f32x4  = __attribute__((ext_vector_type(4))) float;  // 4 fp32

__device__ inline float blo32(u32 u) { union { u32 i; float f; } v; v.i = u << 16; return v.f; }
__device__ inline float bhi32(u32 u) { union { u32 i; float f; } v; v.i = u & 0xFFFF0000u; return v.f; }
__device__ inline float bf2f(us u) { union { u32 i; float f; } v; v.i = ((u32)u) << 16; return v.f; }
__device__ inline us f2bf(float x) {
    union { float f; u32 i; } v; v.f = x;
    u32 r = v.i + 0x7FFFu + ((v.i >> 16) & 1u);
    return (us)(r >> 16);
}

// ---------------------------------------------------------------------------
// K0: probe key_mask storage (int32 vs u8 bool). flag=1 -> u8 storage.
// ---------------------------------------------------------------------------
__global__ void k_mask_probe(const u32* __restrict__ mw, int nwords,
                             int* __restrict__ flag)
{
    u32 any = 0;
    for (int j = blockIdx.x * blockDim.x + threadIdx.x; j < nwords;
         j += gridDim.x * blockDim.x)
        any |= mw[j] & 0xFFFFFF00u;
    if (any) atomicOr(flag, 1);
}

// ---------------------------------------------------------------------------
// K1: QKV projection.  QKV = F @ in_proj_w^T + in_proj_b, split into Q/Fk/Fv.
// ---------------------------------------------------------------------------
__global__ __launch_bounds__(384) void k_qkv(
    const float* __restrict__ F, const float* __restrict__ W,
    const float* __restrict__ B,
    float* __restrict__ Q, float* __restrict__ Fk, float* __restrict__ Fv, int N)
{
    __shared__ float xL[8][CDIM];
    int row0 = blockIdx.x * 8;
    int t = threadIdx.x;
    for (int o = t; o < 8 * CDIM; o += 384) {
        int r = o >> 7, c = o & 127;
        int row = row0 + r;
        xL[r][c] = (row < N) ? F[row * CDIM + c] : 0.f;
    }
    __syncthreads();

    int e = t;  // 0..383
    const float4* W4 = (const float4*)(W + e * CDIM);
    float acc[8] = {0.f,0.f,0.f,0.f,0.f,0.f,0.f,0.f};
    #pragma unroll 8
    for (int c4 = 0; c4 < CDIM / 4; ++c4) {
        float4 w = W4[c4];
        #pragma unroll
        for (int r = 0; r < 8; ++r) {
            const float* x = &xL[r][c4 * 4];
            acc[r] += x[0]*w.x + x[1]*w.y + x[2]*w.z + x[3]*w.w;
        }
    }
    float bv = B[e];
    float* dst; int eo;
    if (e < 128)      { dst = Q;  eo = e; }
    else if (e < 256) { dst = Fk; eo = e - 128; }
    else              { dst = Fv; eo = e - 256; }
    #pragma unroll
    for (int r = 0; r < 8; ++r) {
        int row = row0 + r;
        if (row < N) dst[row * CDIM + eo] = acc[r] + bv;
    }
}

// ---------------------------------------------------------------------------
// K2: attention, one block (256 thr = 4 waves) per query voxel.
// MFMA scores with B-fragment (P hi/lo bf16) built IN REGISTERS by the same
// lanes that consume it (phase-B mapping == B-fragment layout). Only P-hi is
// stored to LDS (for Pbar). qw hi/lo in LDS (8 rows; A rows 8-15 are cndmask
// zeros). Pbar on all 256 threads reading the bf16 hi plane.
//   score[h,k] = ( q_h . Fk[idx_k]_h [f32, wave 3]
//               + qw[h,:] . P[k,:]   [MFMA hi/lo, waves 0-2] ) / 4
//   ctx[c]     = sum_k a[h,k] Fv[idx_k][c]  +  Pbar[h,:] . wv[c,:]
// LDS 27616 B.
// ---------------------------------------------------------------------------
__global__ __launch_bounds__(256, 4) void k_attn(
    const float* __restrict__ coords, const int* __restrict__ kidx,
    const u8* __restrict__ kmask_u8, const int* __restrict__ kmask_i32,
    const int* __restrict__ maskflag,
    const float* __restrict__ Q, const float* __restrict__ Fk,
    const float* __restrict__ Fv,
    const float* __restrict__ wk, const float* __restrict__ wv,
    const float* __restrict__ kpw, const float* __restrict__ kpb,
    float* __restrict__ CTX)
{
    // manual LDS layout (bytes):
    __shared__ __align__(16) u8 SM[27616];
    us*    PH    = (us*)(SM);             // [48][136] P hi        (13056)
    us*    qwH   = (us*)(SM + 13056);     // [8][136]  qw hi       (2176)
    us*    qwL   = (us*)(SM + 15232);     // [8][136]  qw lo       (2176)
    float* scL   = (float*)(SM + 17408);  // [8][49]               (1568)
    float* Ql    = (float*)(SM + 18976);  // [128]                 (512)
    float* rel   = (float*)(SM + 19488);  // [48][3]               (576)
    float* kpw0S = (float*)(SM + 20064);  // [128]                 (512)
    float* kpw1S = (float*)(SM + 20576);  // [128]                 (512)
    float* kpw2S = (float*)(SM + 21088);  // [128]                 (512)
    float* kpbS  = (float*)(SM + 21600);  // [128]                 (512)
    int*   idxl  = (int*)  (SM + 22112);  // [48]                  (192)
    u8*    mskl  = (u8*)   (SM + 22304);  // [48]                  (64)
    float* Pb    = (float*)(SM + 22368);  // [8][132] Pbar         (4224)
    float* pc    = (float*)(SM + 26592);  // [2][128]              (1024)

    int n = blockIdx.x;
    int t = threadIdx.x;
    int w = t >> 6, lane = t & 63;

    // ---- phase A: indices / mask / rel / q row / kpw staging (transposed) ----
    if (t < KNBR) {
        int idx = kidx[n * KNBR + t];
        idxl[t] = idx;
        mskl[t] = maskflag[0] ? kmask_u8[n * KNBR + t]
                              : (u8)kmask_i32[n * KNBR + t];
        rel[t * 3 + 0] = coords[idx * 3 + 0] - coords[n * 3 + 0];
        rel[t * 3 + 1] = coords[idx * 3 + 1] - coords[n * 3 + 1];
        rel[t * 3 + 2] = coords[idx * 3 + 2] - coords[n * 3 + 2];
    }
    if (t < 128) {
        kpw0S[t] = kpw[t * 3 + 0];
        kpw1S[t] = kpw[t * 3 + 1];
        kpw2S[t] = kpw[t * 3 + 2];
        kpbS[t]  = kpb[t];
    } else {
        Ql[t - 128] = Q[n * CDIM + (t - 128)];
    }
    __syncthreads();

    // ---- phase B1: qw = q_h @ wk_h (f32 -> hi/lo bf16 in LDS, 8 rows) ----
    {
        int h = t >> 5, c4 = t & 31;
        const float* qh = Ql + h * DHEAD;
        float a0=0.f, a1=0.f, a2=0.f, a3=0.f;
        #pragma unroll
        for (int d = 0; d < DHEAD; ++d) {
            float q = qh[d];
            float4 wr = *(const float4*)(wk + (size_t)(h * DHEAD + d) * CDIM + c4 * 4);
            a0 += q * wr.x; a1 += q * wr.y; a2 += q * wr.z; a3 += q * wr.w;
        }
        us h0=f2bf(a0), h1=f2bf(a1), h2=f2bf(a2), h3=f2bf(a3);
        us l0=f2bf(a0-bf2f(h0)), l1=f2bf(a1-bf2f(h1)),
           l2=f2bf(a2-bf2f(h2)), l3=f2bf(a3-bf2f(h3));
        uint2 ph; ph.x = (u32)h0 | ((u32)h1 << 16); ph.y = (u32)h2 | ((u32)h3 << 16);
        uint2 pl; pl.x = (u32)l0 | ((u32)l1 << 16); pl.y = (u32)l2 | ((u32)l3 << 16);
        *(uint2*)&qwH[h * 136 + c4 * 4] = ph;
        *(uint2*)&qwL[h * 136 + c4 * 4] = pl;
    }

    // ---- phase B2: waves 0-2: P in registers (B-fragment layout) + PH write;
    //                wave 3: exact f32 q.Fk partial scores ----
    union U8 { bf16x8 v; u32 wd[4]; };
    U8 BH[4], BL[4];
    if (w < 3) {
        int kk = w * 16 + (lane & 15);        // P row this lane owns
        int cb0 = (lane >> 4) * 8;            // c-chunk base
        float r0 = rel[kk * 3], r1 = rel[kk * 3 + 1], r2 = rel[kk * 3 + 2];
        #pragma unroll
        for (int s = 0; s < 4; ++s) {
            int cb = cb0 + s * 32;
            float4 x0 = *(const float4*)&kpw0S[cb], x1 = *(const float4*)&kpw0S[cb + 4];
            float4 y0 = *(const float4*)&kpw1S[cb], y1 = *(const float4*)&kpw1S[cb + 4];
            float4 z0 = *(const float4*)&kpw2S[cb], z1 = *(const float4*)&kpw2S[cb + 4];
            float4 b0 = *(const float4*)&kpbS[cb],  b1 = *(const float4*)&kpbS[cb + 4];
            float p[8];
            p[0] = fmaxf(b0.x + r0*x0.x + r1*y0.x + r2*z0.x, 0.f);
            p[1] = fmaxf(b0.y + r0*x0.y + r1*y0.y + r2*z0.y, 0.f);
            p[2] = fmaxf(b0.z + r0*x0.z + r1*y0.z + r2*z0.z, 0.f);
            p[3] = fmaxf(b0.w + r0*x0.w + r1*y0.w + r2*z0.w, 0.f);
            p[4] = fmaxf(b1.x + r0*x1.x + r1*y1.x + r2*z1.x, 0.f);
            p[5] = fmaxf(b1.y + r0*x1.y + r1*y1.y + r2*z1.y, 0.f);
            p[6] = fmaxf(b1.z + r0*x1.z + r1*y1.z + r2*z1.z, 0.f);
            p[7] = fmaxf(b1.w + r0*x1.w + r1*y1.w + r2*z1.w, 0.f);
            #pragma unroll
            for (int j = 0; j < 4; ++j) {
                us hA = f2bf(p[2*j]), hB = f2bf(p[2*j+1]);
                BH[s].wd[j] = (u32)hA | ((u32)hB << 16);
                us lA = f2bf(p[2*j]   - bf2f(hA));
                us lB = f2bf(p[2*j+1] - bf2f(hB));
                BL[s].wd[j] = (u32)lA | ((u32)lB << 16);
            }
            *(bf16x8*)(PH + kk * 136 + cb) = BH[s].v;   // hi plane for Pbar
        }
    } else {
        #pragma unroll
        for (int i = 0; i < 6; ++i) {
            int o = lane * 6 + i;             // 384 = 48 k x 8 h
            int k = o >> 3, h = o & 7;
            const float* qh = Ql + h * DHEAD;
            const float4* fk = (const float4*)(Fk + (size_t)idxl[k] * CDIM + h * DHEAD);
            float4 f0 = fk[0], f1 = fk[1], f2 = fk[2], f3 = fk[3];
            float s = qh[0]*f0.x + qh[1]*f0.y + qh[2]*f0.z + qh[3]*f0.w
                    + qh[4]*f1.x + qh[5]*f1.y + qh[6]*f1.z + qh[7]*f1.w
                    + qh[8]*f2.x + qh[9]*f2.y + qh[10]*f2.z + qh[11]*f2.w
                    + qh[12]*f3.x + qh[13]*f3.y + qh[14]*f3.z + qh[15]*f3.w;
            scL[h * 49 + k] = s;
        }
    }
    __syncthreads();

    // ---- phase C: MFMA scores (waves 0-2), A=qw from LDS (rows>=8 zero) ----
    if (w < 3) {
        f32x4 acc = {0.f, 0.f, 0.f, 0.f};
        int arow = lane & 15;
        int ko = (lane >> 4) * 8;
        bool aval = arow < 8;
        bf16x8 zz = {0,0,0,0,0,0,0,0};
        #pragma unroll
        for (int s = 0; s < 4; ++s) {
            int c0 = s * 32 + ko;
            bf16x8 ah = aval ? *(const bf16x8*)(qwH + arow * 136 + c0) : zz;
            bf16x8 al = aval ? *(const bf16x8*)(qwL + arow * 136 + c0) : zz;
            acc = __builtin_amdgcn_mfma_f32_16x16x32_bf16(ah, BH[s].v, acc, 0, 0, 0);
            acc = __builtin_amdgcn_mfma_f32_16x16x32_bf16(ah, BL[s].v, acc, 0, 0, 0);
            acc = __builtin_amdgcn_mfma_f32_16x16x32_bf16(al, BH[s].v, acc, 0, 0, 0);
        }
        // combine: D col=lane&15 -> kk, row=(lane>>4)*4+j -> h (rows 0-7 valid)
        if (lane < 32) {
            int kk = w * 16 + (lane & 15);
            int rb = (lane >> 4) * 4;
            u8 mk = mskl[kk];
            #pragma unroll
            for (int j = 0; j < 4; ++j) {
                int h = rb + j;
                float s = acc[j] + scL[h * 49 + kk];
                scL[h * 49 + kk] = mk ? -1e30f : s * 0.25f;
            }
        }
    }
    __syncthreads();

    // ---- phase D: softmax (32 lanes per head) ----
    {
        int h = t >> 5, l32 = t & 31;
        float* sc = scL + h * 49;
        float v0 = sc[l32];
        float v1 = (l32 < KNBR - 32) ? sc[l32 + 32] : -1e30f;
        float m = fmaxf(v0, v1);
        #pragma unroll
        for (int off = 16; off >= 1; off >>= 1)
            m = fmaxf(m, __shfl_xor(m, off, 32));
        float e0 = __expf(v0 - m);
        float e1 = (l32 < KNBR - 32) ? __expf(v1 - m) : 0.f;
        float s = e0 + e1;
        #pragma unroll
        for (int off = 16; off >= 1; off >>= 1)
            s += __shfl_xor(s, off, 32);
        float inv = 1.f / s;
        sc[l32] = e0 * inv;
        if (l32 < KNBR - 32) sc[l32 + 32] = e1 * inv;
    }
    __syncthreads();

    // ---- phase E: Pbar[h][:] = attn[h,:] @ P_hi (all 256 threads) ----
    {
        int h = t >> 5, c4 = t & 31;
        float a0 = 0.f, a1 = 0.f, a2 = 0.f, a3 = 0.f;
        const float* sc = scL + h * 49;
        #pragma unroll 6
        for (int k = 0; k < KNBR; ++k) {
            float p = sc[k];
            uint2 x = *(const uint2*)&PH[k * 136 + c4 * 4];
            a0 += p * blo32(x.x); a1 += p * bhi32(x.x);
            a2 += p * blo32(x.y); a3 += p * bhi32(x.y);
        }
        *(float4*)&Pb[h * 132 + c4 * 4] = make_float4(a0, a1, a2, a3);
    }
    __syncthreads();

    // ---- phase F: ctx = attn @ Fv (coalesced gather) + Pbar . wv ----
    {
        int c = t & 127, half = t >> 7;
        int h = c >> 4;
        const float* sc = scL + h * 49;
        float accF = 0.f;
        #pragma unroll 4
        for (int kk = 0; kk < 24; ++kk) {
            int k = half * 24 + kk;
            accF += sc[k] * Fv[(size_t)idxl[k] * CDIM + c];
        }
        const float4* wr = (const float4*)(wv + (size_t)c * CDIM) + half * 16;
        const float4* pb4 = (const float4*)(Pb + h * 132) + half * 16;
        #pragma unroll 4
        for (int j = 0; j < 16; ++j) {
            float4 wq = wr[j], p = pb4[j];
            accF += wq.x*p.x + wq.y*p.y + wq.z*p.z + wq.w*p.w;
        }
        pc[half * 128 + c] = accF;
    }
    __syncthreads();
    if (t < CDIM) CTX[n * CDIM + t] = pc[t] + pc[128 + t];
}

// ---------------------------------------------------------------------------
// K3/K6: 128->128 GEMM + bias (+ optional residual) + LayerNorm (+ opt relu)
// ---------------------------------------------------------------------------
__global__ __launch_bounds__(256) void k_proj_ln(
    const float* __restrict__ X, const float* __restrict__ RES,
    const float* __restrict__ W, const float* __restrict__ B,
    const float* __restrict__ G, const float* __restrict__ LB,
    float* __restrict__ OUT, int N, int relu_out)
{
    __shared__ float xL[16][CDIM];
    __shared__ float aL[16][CDIM + 4];
    __shared__ float mu[16], rs[16];
    int row0 = blockIdx.x * 16;
    int t = threadIdx.x;
    for (int o = t; o < 16 * CDIM; o += 256) {
        int r = o >> 7, c = o & 127;
        int row = row0 + r;
        xL[r][c] = (row < N) ? X[row * CDIM + c] : 0.f;
    }
    __syncthreads();

    int e = t & 127, rh = t >> 7;
    const float4* W4 = (const float4*)(W + e * CDIM);
    float acc[8] = {0.f,0.f,0.f,0.f,0.f,0.f,0.f,0.f};
    #pragma unroll 8
    for (int c4 = 0; c4 < CDIM / 4; ++c4) {
        float4 w = W4[c4];
        #pragma unroll
        for (int i = 0; i < 8; ++i) {
            const float* x = &xL[rh * 8 + i][c4 * 4];
            acc[i] += x[0]*w.x + x[1]*w.y + x[2]*w.z + x[3]*w.w;
        }
    }
    float bv = B[e];
    #pragma unroll
    for (int i = 0; i < 8; ++i) {
        int r = rh * 8 + i, row = row0 + r;
        float a = acc[i] + bv;
        if (RES != nullptr && row < N) a += RES[row * CDIM + e];
        aL[r][e] = a;
    }
    __syncthreads();

    {
        int r = t >> 4, j = t & 15;
        float s = 0.f;
        #pragma unroll
        for (int jj = 0; jj < 8; ++jj) s += aL[r][j * 8 + jj];
        #pragma unroll
        for (int off = 8; off >= 1; off >>= 1) s += __shfl_xor(s, off, 16);
        float mean = s * (1.f / 128.f);
        float v = 0.f;
        #pragma unroll
        for (int jj = 0; jj < 8; ++jj) {
            float d = aL[r][j * 8 + jj] - mean; v += d * d;
        }
        #pragma unroll
        for (int off = 8; off >= 1; off >>= 1) v += __shfl_xor(v, off, 16);
        if (j == 0) { mu[r] = mean; rs[r] = rsqrtf(v * (1.f / 128.f) + 1e-5f); }
    }
    __syncthreads();

    for (int o = t; o < 16 * CDIM; o += 256) {
        int r = o >> 7, c = o & 127;
        int row = row0 + r;
        if (row < N) {
            float y = (aL[r][c] - mu[r]) * rs[r] * G[c] + LB[c];
            if (relu_out) y = fmaxf(y, 0.f);
            OUT[row * CDIM + c] = y;
        }
    }
}

// ---------------------------------------------------------------------------
// K4: ff1: hid = relu(x1 @ W1^T + b1), 128 -> 256.
// ---------------------------------------------------------------------------
__global__ __launch_bounds__(256) void k_ff1(
    const float* __restrict__ X, const float* __restrict__ W,
    const float* __restrict__ B, float* __restrict__ HID, int N)
{
    __shared__ float xL[8][CDIM];
    int row0 = blockIdx.x * 8;
    int t = threadIdx.x;
    for (int o = t; o < 8 * CDIM; o += 256) {
        int r = o >> 7, c = o & 127;
        int row = row0 + r;
        xL[r][c] = (row < N) ? X[row * CDIM + c] : 0.f;
    }
    __syncthreads();

    int e = t;
    const float4* W4 = (const float4*)(W + e * CDIM);
    float acc[8] = {0.f,0.f,0.f,0.f,0.f,0.f,0.f,0.f};
    #pragma unroll 8
    for (int c4 = 0; c4 < CDIM / 4; ++c4) {
        float4 w = W4[c4];
        #pragma unroll
        for (int r = 0; r < 8; ++r) {
            const float* x = &xL[r][c4 * 4];
            acc[r] += x[0]*w.x + x[1]*w.y + x[2]*w.z + x[3]*w.w;
        }
    }
    float bv = B[e];
    #pragma unroll
    for (int r = 0; r < 8; ++r) {
        int row = row0 + r;
        if (row < N) HID[row * FFDIM + e] = fmaxf(acc[r] + bv, 0.f);
    }
}

// ---------------------------------------------------------------------------
// K5: x2 = LN(x1 + hid @ W2^T + b2), 256 -> 128.
// ---------------------------------------------------------------------------
__global__ __launch_bounds__(256) void k_ff2_ln(
    const float* __restrict__ HID, const float* __restrict__ RES,
    const float* __restrict__ W, const float* __restrict__ B,
    const float* __restrict__ G, const float* __restrict__ LB,
    float* __restrict__ OUT, int N)
{
    __shared__ float xL[16][FFDIM];
    __shared__ float aL[16][CDIM + 4];
    __shared__ float mu[16], rs[16];
    int row0 = blockIdx.x * 16;
    int t = threadIdx.x;
    for (int o = t; o < 16 * FFDIM; o += 256) {
        int r = o >> 8, c = o & 255;
        int row = row0 + r;
        xL[r][c] = (row < N) ? HID[row * FFDIM + c] : 0.f;
    }
    __syncthreads();

    int e = t & 127, rh = t >> 7;
    const float4* W4 = (const float4*)(W + e * FFDIM);
    float acc[8] = {0.f,0.f,0.f,0.f,0.f,0.f,0.f,0.f};
    #pragma unroll 8
    for (int c4 = 0; c4 < FFDIM / 4; ++c4) {
        float4 w = W4[c4];
        #pragma unroll
        for (int i = 0; i < 8; ++i) {
            const float* x = &xL[rh * 8 + i][c4 * 4];
            acc[i] += x[0]*w.x + x[1]*w.y + x[2]*w.z + x[3]*w.w;
        }
    }
    float bv = B[e];
    #pragma unroll
    for (int i = 0; i < 8; ++i) {
        int r = rh * 8 + i, row = row0 + r;
        float a = acc[i] + bv;
        if (row < N) a += RES[row * CDIM + e];
        aL[r][e] = a;
    }
    __syncthreads();

    {
        int r = t >> 4, j = t & 15;
        float s = 0.f;
        #pragma unroll
        for (int jj = 0; jj < 8; ++jj) s += aL[r][j * 8 + jj];
        #pragma unroll
        for (int off = 8; off >= 1; off >>= 1) s += __shfl_xor(s, off, 16);
        float mean = s * (1.f / 128.f);
        float v = 0.f;
        #pragma unroll
        for (int jj = 0; jj < 8; ++jj) {
            float d = aL[r][j * 8 + jj] - mean; v += d * d;
        }
        #pragma unroll
        for (int off = 8; off >= 1; off >>= 1) v += __shfl_xor(v, off, 16);
        if (j == 0) { mu[r] = mean; rs[r] = rsqrtf(v * (1.f / 128.f) + 1e-5f); }
    }
    __syncthreads();

    for (int o = t; o < 16 * CDIM; o += 256) {
        int r = o >> 7, c = o & 127;
        int row = row0 + r;
        if (row < N)
            OUT[row * CDIM + c] = (aL[r][c] - mu[r]) * rs[r] * G[c] + LB[c];
    }
}

// ---------------------------------------------------------------------------
extern "C" void kernel_launch(void* const* d_in, const int* in_sizes, int n_in,
                              void* d_out, int out_size, void* d_ws, size_t ws_size,
                              hipStream_t stream)
{
    const float* F      = (const float*)d_in[0];
    const float* coords = (const float*)d_in[1];
    const int*   kidx   = (const int*)d_in[2];
    const void*  kmask  = d_in[3];
    const float* ipw    = (const float*)d_in[4];
    const float* ipb    = (const float*)d_in[5];
    const float* opw    = (const float*)d_in[6];
    const float* opb    = (const float*)d_in[7];
    const float* kpw    = (const float*)d_in[8];
    const float* kpb    = (const float*)d_in[9];
    const float* ln1g   = (const float*)d_in[10];
    const float* ln1b   = (const float*)d_in[11];
    const float* ln2g   = (const float*)d_in[12];
    const float* ln2b   = (const float*)d_in[13];
    const float* w1     = (const float*)d_in[14];
    const float* b1     = (const float*)d_in[15];
    const float* w2     = (const float*)d_in[16];
    const float* b2     = (const float*)d_in[17];
    const float* ow     = (const float*)d_in[18];
    const float* ob     = (const float*)d_in[19];
    const float* ln3g   = (const float*)d_in[20];
    const float* ln3b   = (const float*)d_in[21];

    int N = in_sizes[0] / CDIM;
    size_t NC = (size_t)N * CDIM;

    float* ws  = (float*)d_ws;
    float* Q   = ws;                 // N*128
    float* Fk  = ws + NC;            // N*128
    float* Fv  = ws + 2 * NC;        // N*128
    float* CTX = ws + 3 * NC;        // N*128
    float* X1  = Q;                  // reuse (Q dead after attention)
    float* HID = ws + NC;            // N*256, over Fk+Fv (dead after attention)
    float* X2  = CTX;                // reuse (CTX dead after K3)
    int* mflag = (int*)(ws + 4 * NC);

    const float* wk = ipw + CDIM * CDIM;
    const float* wv = ipw + 2 * CDIM * CDIM;

    hipMemsetAsync(mflag, 0, sizeof(int), stream);
    int nwords = (N * KNBR) / 4;
    k_mask_probe<<<256, 256, 0, stream>>>((const u32*)kmask, nwords, mflag);

    k_qkv<<<(N + 7) / 8, 384, 0, stream>>>(F, ipw, ipb, Q, Fk, Fv, N);
    k_attn<<<N, 256, 0, stream>>>(coords, kidx, (const u8*)kmask,
                                  (const int*)kmask, mflag, Q, Fk, Fv,
                                  wk, wv, kpw, kpb, CTX);
    k_proj_ln<<<(N + 15) / 16, 256, 0, stream>>>(CTX, F, opw, opb,
                                                 ln1g, ln1b, X1, N, 0);
    k_ff1<<<(N + 7) / 8, 256, 0, stream>>>(X1, w1, b1, HID, N);
    k_ff2_ln<<<(N + 15) / 16, 256, 0, stream>>>(HID, X1, w2, b2,
                                                ln2g, ln2b, X2, N);
    k_proj_ln<<<(N + 15) / 16, 256, 0, stream>>>(X2, nullptr, ow, ob,
                                                 ln3g, ln3b, (float*)d_out, N, 1);
}